// Round 2
// baseline (1028.474 us; speedup 1.0000x reference)
//
#include <hip/hip_runtime.h>
#include <hip/hip_bf16.h>

typedef __hip_bfloat16 bf16;

#define NPIX 3136   // 56*56
#define HDIM 56
#define CDIM 256

static __device__ __forceinline__ float b2f(bf16 v){ return __bfloat162float(v); }
static __device__ __forceinline__ bf16  f2b(float v){ return __float2bfloat16(v); }

struct B4 { bf16 a, b, c, d; };

// ---- fold region float offsets ----
#define O_KE_S 0
#define O_KE_B 256
#define O_E1_S 512
#define O_E1_B 640
#define O_C1_S 768
#define O_C1_B 1024
#define O_B2_S 1280
#define O_B2_B 1536
#define O_S1_S 1792
#define O_S1_B 1920
#define O_E2B  2048
#define O_GN_MU 2336
#define O_GN_RS 2848
#define O_GAP   3360
#define O_ATT   7456

// ---------------- convert x (fp32) -> bf16 ----------------
__global__ void cvt_bf16(const float* __restrict__ src, bf16* __restrict__ dst)
{
    long i = (long)blockIdx.x * 256 + threadIdx.x;
    float4 v = ((const float4*)src)[i];
    B4 o;
    o.a = f2b(v.x); o.b = f2b(v.y); o.c = f2b(v.z); o.d = f2b(v.w);
    ((B4*)dst)[i] = o;
}

// ---------------- fold BN params (eval mode): s = g*rsqrt(v+eps), b' = b - m*s ----
__global__ void fold_params(
    const float* keg, const float* keb, const float* kem, const float* kev,
    const float* e1g, const float* e1b, const float* e1m, const float* e1v,
    const float* e2b,
    const float* c1g, const float* c1b, const float* c1m, const float* c1v,
    const float* b2g, const float* b2b, const float* b2m, const float* b2v,
    const float* s1g, const float* s1bb, const float* s1m, const float* s1v,
    float* o)
{
    int t = threadIdx.x;  // 512 threads
    const float eps = 1e-5f;
    if (t < 256) {
        float s = keg[t] * rsqrtf(kev[t] + eps);
        o[O_KE_S + t] = s; o[O_KE_B + t] = keb[t] - kem[t] * s;
        s = c1g[t] * rsqrtf(c1v[t] + eps);
        o[O_C1_S + t] = s; o[O_C1_B + t] = c1b[t] - c1m[t] * s;
        s = b2g[t] * rsqrtf(b2v[t] + eps);
        o[O_B2_S + t] = s; o[O_B2_B + t] = b2b[t] - b2m[t] * s;
    }
    if (t < 128) {
        float s = e1g[t] * rsqrtf(e1v[t] + eps);
        o[O_E1_S + t] = s; o[O_E1_B + t] = e1b[t] - e1m[t] * s;
        s = s1g[t] * rsqrtf(s1v[t] + eps);
        o[O_S1_S + t] = s; o[O_S1_B + t] = s1bb[t] - s1m[t] * s;
    }
    if (t < 288) o[O_E2B + t] = e2b[t];
}

// ---------------- grouped 3x3 conv + BN + ReLU ----------------
// grid (56, 4, 16) = (h, group, batch), block 64 (thread = co within group)
__global__ void gconv3x3(const bf16* __restrict__ x, const float* __restrict__ w,
                         const float* __restrict__ scale, const float* __restrict__ bias,
                         bf16* __restrict__ kout)
{
    int h = blockIdx.x, g = blockIdx.y, b = blockIdx.z;
    int t = threadIdx.x;            // local co 0..63
    int co = g * 64 + t;
    __shared__ float xs[3][64];     // rows h-1..h+1, cols -1..56 -> index col+1 (58 used)
    float acc[HDIM];
    #pragma unroll
    for (int i = 0; i < HDIM; i++) acc[i] = 0.f;

    for (int ci = 0; ci < 64; ci++) {
        const bf16* xrow = x + ((long)(b * CDIM + g * 64 + ci)) * NPIX;
        __syncthreads();            // protect previous iteration's reads
        for (int e = t; e < 174; e += 64) {
            int r = e / 58, cc = e % 58;
            int hh = h - 1 + r, ww = cc - 1;
            float v = 0.f;
            if (hh >= 0 && hh < HDIM && ww >= 0 && ww < HDIM) v = b2f(xrow[hh * HDIM + ww]);
            xs[r][cc] = v;
        }
        float wt[9];
        const float* wp = w + ((long)co * 64 + ci) * 9;
        #pragma unroll
        for (int tp = 0; tp < 9; tp++) wt[tp] = wp[tp];
        __syncthreads();
        #pragma unroll
        for (int ww = 0; ww < HDIM; ww++) {
            float a = acc[ww];
            #pragma unroll
            for (int dh = 0; dh < 3; dh++)
                #pragma unroll
                for (int dw = 0; dw < 3; dw++)
                    a += xs[dh][ww + dw] * wt[dh * 3 + dw];
            acc[ww] = a;
        }
    }
    float s = scale[co], bi = bias[co];
    bf16* dst = kout + ((long)(b * CDIM + co)) * NPIX + h * HDIM;
    #pragma unroll
    for (int ww = 0; ww < HDIM; ww++)
        dst[ww] = f2b(fmaxf(acc[ww] * s + bi, 0.f));
}

// ---------------- 1x1 conv as per-batch GEMM: Y(M,N) = W(M,K) @ X(K,N) ----------------
// MODE 0: BN+ReLU   MODE 1: +bias only   MODE 2: BN only
// X channels [0,K0) come from X0, [K0,K) from X1 (for the concat input)
#define TS 64
#define BK 16
template<int MODE>
__global__ void gemm1x1(const float* __restrict__ W, const bf16* __restrict__ X0,
                        const bf16* __restrict__ X1, int M, int K, int K0,
                        const float* __restrict__ scale, const float* __restrict__ bias,
                        bf16* __restrict__ Y)
{
    int b = blockIdx.z;
    int m0 = blockIdx.y * TS;
    int n0 = blockIdx.x * TS;
    __shared__ float Ws[BK][TS + 1];
    __shared__ float Xs[BK][TS + 1];
    int tid = threadIdx.x;              // 256
    int tm = (tid / 16) * 4;
    int tn = (tid % 16) * 4;
    float acc[4][4] = {};
    for (int k0 = 0; k0 < K; k0 += BK) {
        #pragma unroll
        for (int i = 0; i < 4; i++) {   // W tile: 16x64 = 1024
            int e = tid + i * 256;
            int kk = e % BK, mm = e / BK;
            int m = m0 + mm;
            Ws[kk][mm] = (m < M) ? W[(long)m * K + k0 + kk] : 0.f;
        }
        #pragma unroll
        for (int i = 0; i < 4; i++) {   // X tile
            int e = tid + i * 256;
            int nn = e % TS, kk = e / TS;
            int k = k0 + kk, n = n0 + nn;
            float v;
            if (k < K0) v = b2f(X0[((long)b * K0 + k) * NPIX + n]);
            else        v = b2f(X1[((long)b * (K - K0) + (k - K0)) * NPIX + n]);
            Xs[kk][nn] = v;
        }
        __syncthreads();
        #pragma unroll
        for (int kk = 0; kk < BK; kk++) {
            float wv[4], xv[4];
            #pragma unroll
            for (int i = 0; i < 4; i++) wv[i] = Ws[kk][tm + i];
            #pragma unroll
            for (int j = 0; j < 4; j++) xv[j] = Xs[kk][tn + j];
            #pragma unroll
            for (int i = 0; i < 4; i++)
                #pragma unroll
                for (int j = 0; j < 4; j++)
                    acc[i][j] += wv[i] * xv[j];
        }
        __syncthreads();
    }
    #pragma unroll
    for (int i = 0; i < 4; i++) {
        int m = m0 + tm + i;
        if (m >= M) continue;
        float s = 1.f, bi = 0.f;
        if (MODE == 0 || MODE == 2) { s = scale[m]; bi = bias[m]; }
        if (MODE == 1) { bi = bias[m]; }
        bf16* dst = Y + ((long)b * M + m) * NPIX + n0 + tn;
        #pragma unroll
        for (int j = 0; j < 4; j++) {
            float v = acc[i][j] * s + bi;
            if (MODE == 0) v = fmaxf(v, 0.f);
            dst[j] = f2b(v);
        }
    }
}

// ---------------- GroupNorm stats: one block per (b, grp); 9 contiguous channels ----
__global__ void gnstats(const bf16* __restrict__ wemb, float* __restrict__ mu_o, float* __restrict__ rs_o)
{
    int bg = blockIdx.x;                // b*32+grp ; channel base = bg*9 (288 = 32*9)
    const bf16* base = wemb + (long)bg * 9 * NPIX;
    float s = 0.f, sq = 0.f;
    for (int i = threadIdx.x; i < 9 * NPIX; i += 256) {
        float v = b2f(base[i]); s += v; sq += v * v;
    }
    __shared__ float ss[256], sb[256];
    int t = threadIdx.x;
    ss[t] = s; sb[t] = sq;
    __syncthreads();
    for (int o = 128; o > 0; o >>= 1) {
        if (t < o) { ss[t] += ss[t + o]; sb[t] += sb[t + o]; }
        __syncthreads();
    }
    if (t == 0) {
        float m = ss[0] / 28224.f;
        float var = sb[0] / 28224.f - m * m;
        mu_o[bg] = m; rs_o[bg] = rsqrtf(fmaxf(var, 0.f) + 1e-5f);
    }
}

// ---------------- dynamic local conv + BN(b2) + swish ----------------
__global__ void dynconv(const bf16* __restrict__ xq, const bf16* __restrict__ wemb,
                        const float* __restrict__ gmu, const float* __restrict__ grs,
                        const float* __restrict__ gng, const float* __restrict__ gnb,
                        const float* __restrict__ b2s, const float* __restrict__ b2b,
                        bf16* __restrict__ y)
{
    long idx = (long)blockIdx.x * 256 + threadIdx.x;
    int p = (int)(idx % NPIX);
    long bcl = idx / NPIX;
    int c = (int)(bcl % CDIM);
    int b = (int)(bcl / CDIM);
    int h = p / HDIM, w = p % HDIM;
    int grp = c >> 3;
    float mu = gmu[b * 32 + grp], rs = grs[b * 32 + grp];
    const bf16* xbase = xq + bcl * NPIX;
    const bf16* wbase = wemb + ((long)(b * 288 + grp * 9)) * NPIX + p;
    float acc = 0.f;
    #pragma unroll
    for (int dh = -1; dh <= 1; dh++) {
        int hh = h + dh;
        bool hv = (hh >= 0) && (hh < HDIM);
        #pragma unroll
        for (int dw = -1; dw <= 1; dw++) {
            int tap = (dh + 1) * 3 + (dw + 1);
            int ww = w + dw;
            bool ok = hv && (ww >= 0) && (ww < HDIM);
            float xv = ok ? b2f(xbase[hh * HDIM + ww]) : 0.f;
            int ch = grp * 9 + tap;
            float wv = (b2f(wbase[(long)tap * NPIX]) - mu) * rs * gng[ch] + gnb[ch];
            acc += xv * wv;
        }
    }
    float v = acc * b2s[c] + b2b[c];
    y[idx] = f2b(v / (1.f + __expf(-v)));
}

// ---------------- GAP over (y + k) ----------------
__global__ void gapk(const bf16* __restrict__ y, const bf16* __restrict__ k, float* __restrict__ gap)
{
    int bc = blockIdx.x;
    const bf16* yp = y + (long)bc * NPIX;
    const bf16* kp = k + (long)bc * NPIX;
    float s = 0.f;
    for (int i = threadIdx.x; i < NPIX; i += 256) s += b2f(yp[i]) + b2f(kp[i]);
    __shared__ float ss[256];
    int t = threadIdx.x;
    ss[t] = s; __syncthreads();
    for (int o = 128; o > 0; o >>= 1) {
        if (t < o) ss[t] += ss[t + o];
        __syncthreads();
    }
    if (t == 0) gap[bc] = ss[0] / (float)NPIX;
}

// ---------------- split attention: conv1 + bias + BN + ReLU, conv2 + bias, pair softmax ----
__global__ void attnk(const float* __restrict__ gap,
                      const float* __restrict__ s1w, const float* __restrict__ s1b,
                      const float* __restrict__ s1s, const float* __restrict__ s1bi,
                      const float* __restrict__ s2w, const float* __restrict__ s2b,
                      float* __restrict__ att)
{
    int b = blockIdx.x, t = threadIdx.x;   // 128 threads
    __shared__ float g[256], a1[128];
    for (int i = t; i < 256; i += 128) g[i] = gap[b * 256 + i];
    __syncthreads();
    float s = 0.f;
    for (int ci = 0; ci < 256; ci++) s += s1w[t * 256 + ci] * g[ci];
    s += s1b[t];
    s = s * s1s[t] + s1bi[t];
    a1[t] = fmaxf(s, 0.f);
    __syncthreads();
    for (int c = t; c < 256; c += 128) {
        float v0 = s2b[2 * c], v1 = s2b[2 * c + 1];
        for (int ci = 0; ci < 128; ci++) {
            float av = a1[ci];
            v0 += s2w[(2 * c) * 128 + ci] * av;
            v1 += s2w[(2 * c + 1) * 128 + ci] * av;
        }
        float m = fmaxf(v0, v1);
        float e0 = __expf(v0 - m), e1 = __expf(v1 - m);
        float inv = 1.f / (e0 + e1);
        att[(b * 256 + c) * 2 + 0] = e0 * inv;
        att[(b * 256 + c) * 2 + 1] = e1 * inv;
    }
}

// ---------------- final combine: out = y*a0 + k*a1 (fp32 out) ----------------
__global__ void finalk(const bf16* __restrict__ y, const bf16* __restrict__ k,
                       const float* __restrict__ att, float* __restrict__ out)
{
    long i4 = (long)blockIdx.x * 256 + threadIdx.x;
    long base = i4 * 4;
    int bc = (int)(base / NPIX);
    float a0 = att[bc * 2], a1 = att[bc * 2 + 1];
    B4 yv = ((const B4*)y)[i4];
    B4 kv = ((const B4*)k)[i4];
    float4 o;
    o.x = b2f(yv.a) * a0 + b2f(kv.a) * a1;
    o.y = b2f(yv.b) * a0 + b2f(kv.b) * a1;
    o.z = b2f(yv.c) * a0 + b2f(kv.c) * a1;
    o.w = b2f(yv.d) * a0 + b2f(kv.d) * a1;
    ((float4*)out)[i4] = o;
}

extern "C" void kernel_launch(void* const* d_in, const int* in_sizes, int n_in,
                              void* d_out, int out_size, void* d_ws, size_t ws_size,
                              hipStream_t stream)
{
    const float* x    = (const float*)d_in[0];
    const float* ke_w = (const float*)d_in[1];
    const float* ke_g = (const float*)d_in[2];
    const float* ke_b = (const float*)d_in[3];
    const float* ke_m = (const float*)d_in[4];
    const float* ke_v = (const float*)d_in[5];
    const float* e1_w = (const float*)d_in[6];
    const float* e1_g = (const float*)d_in[7];
    const float* e1_b = (const float*)d_in[8];
    const float* e1_m = (const float*)d_in[9];
    const float* e1_v = (const float*)d_in[10];
    const float* e2_w = (const float*)d_in[11];
    const float* e2_b = (const float*)d_in[12];
    const float* gng  = (const float*)d_in[13];
    const float* gnb  = (const float*)d_in[14];
    const float* c1_w = (const float*)d_in[15];
    const float* c1_g = (const float*)d_in[16];
    const float* c1_b = (const float*)d_in[17];
    const float* c1_m = (const float*)d_in[18];
    const float* c1_v = (const float*)d_in[19];
    const float* b2_g = (const float*)d_in[20];
    const float* b2_b = (const float*)d_in[21];
    const float* b2_m = (const float*)d_in[22];
    const float* b2_v = (const float*)d_in[23];
    const float* s1_w = (const float*)d_in[24];
    const float* s1_b = (const float*)d_in[25];
    const float* s1_g = (const float*)d_in[26];
    const float* s1_bb= (const float*)d_in[27];
    const float* s1_m = (const float*)d_in[28];
    const float* s1_v = (const float*)d_in[29];
    const float* s2_w = (const float*)d_in[30];
    const float* s2_b = (const float*)d_in[31];

    float* fold = (float*)d_ws;
    bf16* wsb   = (bf16*)((char*)d_ws + 65536);
    // region layout (bf16 elements), with aliasing:
    //   R0: xb (then yb after last xb read)     12,845,056
    //   R1: k_buf                               12,845,056
    //   R2: wemb                                14,450,688
    //   R3: w1 (6.4M, dead after e2) then xq    12,845,056
    bf16* xb    = wsb;
    bf16* yb    = wsb;                           // aliases xb (xb dead before dynconv)
    bf16* k_buf = wsb + 12845056L;
    bf16* wemb  = k_buf + 12845056L;
    bf16* w1    = wemb + 14450688L;
    bf16* xq    = w1;                            // aliases w1 region (w1 dead before c1 gemm)

    fold_params<<<dim3(1), dim3(512), 0, stream>>>(
        ke_g, ke_b, ke_m, ke_v, e1_g, e1_b, e1_m, e1_v, e2_b,
        c1_g, c1_b, c1_m, c1_v, b2_g, b2_b, b2_m, b2_v,
        s1_g, s1_bb, s1_m, s1_v, fold);

    cvt_bf16<<<dim3(12544), dim3(256), 0, stream>>>(x, xb);

    gconv3x3<<<dim3(56, 4, 16), dim3(64), 0, stream>>>(
        xb, ke_w, fold + O_KE_S, fold + O_KE_B, k_buf);

    gemm1x1<0><<<dim3(49, 2, 16), dim3(256), 0, stream>>>(
        e1_w, xb, k_buf, 128, 512, 256, fold + O_E1_S, fold + O_E1_B, w1);

    gemm1x1<1><<<dim3(49, 5, 16), dim3(256), 0, stream>>>(
        e2_w, w1, (const bf16*)nullptr, 288, 128, 128, (const float*)nullptr, fold + O_E2B, wemb);

    gnstats<<<dim3(512), dim3(256), 0, stream>>>(wemb, fold + O_GN_MU, fold + O_GN_RS);

    gemm1x1<2><<<dim3(49, 4, 16), dim3(256), 0, stream>>>(
        c1_w, xb, (const bf16*)nullptr, 256, 256, 256, fold + O_C1_S, fold + O_C1_B, xq);

    dynconv<<<dim3(50176), dim3(256), 0, stream>>>(
        xq, wemb, fold + O_GN_MU, fold + O_GN_RS, gng, gnb,
        fold + O_B2_S, fold + O_B2_B, yb);

    gapk<<<dim3(4096), dim3(256), 0, stream>>>(yb, k_buf, fold + O_GAP);

    attnk<<<dim3(16), dim3(128), 0, stream>>>(
        fold + O_GAP, s1_w, s1_b, fold + O_S1_S, fold + O_S1_B, s2_w, s2_b, fold + O_ATT);

    finalk<<<dim3(12544), dim3(256), 0, stream>>>(yb, k_buf, fold + O_ATT, (float*)d_out);
}

// Round 3
// 390.806 us; speedup vs baseline: 2.6317x; 2.6317x over previous
//
#include <hip/hip_runtime.h>
#include <hip/hip_bf16.h>

typedef __hip_bfloat16 bf16;
typedef float f32x4 __attribute__((ext_vector_type(4)));
typedef short s16x8 __attribute__((ext_vector_type(8)));

#define NPIX 3136   // 56*56
#define HDIM 56
#define CDIM 256

static __device__ __forceinline__ float b2f(bf16 v){ return __bfloat162float(v); }
static __device__ __forceinline__ bf16  f2b(float v){ return __float2bfloat16(v); }

// ---- fold region float offsets ----
#define O_KE_S 0
#define O_KE_B 256
#define O_E1_S 512
#define O_E1_B 640
#define O_C1_S 768
#define O_C1_B 1024
#define O_B2_S 1280
#define O_B2_B 1536
#define O_S1_S 1792
#define O_S1_B 1920
#define O_E2B  2048
#define O_GN_MU 2336
#define O_GN_RS 2848
#define O_GAP   3360
#define O_ATT   7456

// ---------------- fold BN params ----------------
__global__ void fold_params(
    const float* keg, const float* keb, const float* kem, const float* kev,
    const float* e1g, const float* e1b, const float* e1m, const float* e1v,
    const float* e2b,
    const float* c1g, const float* c1b, const float* c1m, const float* c1v,
    const float* b2g, const float* b2b, const float* b2m, const float* b2v,
    const float* s1g, const float* s1bb, const float* s1m, const float* s1v,
    float* o)
{
    int t = threadIdx.x;  // 512 threads
    const float eps = 1e-5f;
    if (t < 256) {
        float s = keg[t] * rsqrtf(kev[t] + eps);
        o[O_KE_S + t] = s; o[O_KE_B + t] = keb[t] - kem[t] * s;
        s = c1g[t] * rsqrtf(c1v[t] + eps);
        o[O_C1_S + t] = s; o[O_C1_B + t] = c1b[t] - c1m[t] * s;
        s = b2g[t] * rsqrtf(b2v[t] + eps);
        o[O_B2_S + t] = s; o[O_B2_B + t] = b2b[t] - b2m[t] * s;
    }
    if (t < 128) {
        float s = e1g[t] * rsqrtf(e1v[t] + eps);
        o[O_E1_S + t] = s; o[O_E1_B + t] = e1b[t] - e1m[t] * s;
        s = s1g[t] * rsqrtf(s1v[t] + eps);
        o[O_S1_S + t] = s; o[O_S1_B + t] = s1bb[t] - s1m[t] * s;
    }
    if (t < 288) o[O_E2B + t] = e2b[t];
}

__global__ void zero_gap(float* gap) { gap[blockIdx.x * 256 + threadIdx.x] = 0.f; }

// ---------------- weight converts ----------------
__global__ void cvt_w(const float* __restrict__ src, bf16* __restrict__ dst, int n)
{
    int i = blockIdx.x * 256 + threadIdx.x;
    if (i < n) dst[i] = f2b(src[i]);
}

// ke_w (256,64,3,3) fp32 -> wT[g][tap][co_l][ci] bf16
__global__ void make_kewT(const float* __restrict__ kew, bf16* __restrict__ dst)
{
    int i = blockIdx.x * 256 + threadIdx.x;   // 147456
    int ci = i & 63, co_l = (i >> 6) & 63;
    int gt = i >> 12;
    int tap = gt % 9, g = gt / 9;
    int co = g * 64 + co_l;
    dst[i] = f2b(kew[(co * 64 + ci) * 9 + tap]);
}

// ---------------- x: fp32 NCHW -> bf16 NHWC via LDS transpose ----------------
// grid (49, 16), block 256
__global__ __launch_bounds__(256) void cvt_x(const float* __restrict__ x, bf16* __restrict__ xh)
{
    int b = blockIdx.y;
    int p0 = blockIdx.x * 64;
    __shared__ bf16 T[64][264];
    int t = threadIdx.x;
    for (int it = 0; it < 16; it++) {
        int slot = t + it * 256;          // 4096 = 256c * 16 chunks
        int c = slot >> 4, ch4 = slot & 15;
        float4 v = *(const float4*)(x + ((long)b * CDIM + c) * NPIX + p0 + ch4 * 4);
        T[ch4 * 4 + 0][c] = f2b(v.x);
        T[ch4 * 4 + 1][c] = f2b(v.y);
        T[ch4 * 4 + 2][c] = f2b(v.z);
        T[ch4 * 4 + 3][c] = f2b(v.w);
    }
    __syncthreads();
    for (int it = 0; it < 8; it++) {
        int slot = t + it * 256;          // 2048 = 64p * 32 chunks
        int p = slot >> 5, cc = slot & 31;
        *(float4*)(xh + ((long)b * NPIX + p0 + p) * CDIM + cc * 8) = *(const float4*)&T[p][cc * 8];
    }
}

// ---------------- grouped 3x3 conv as per-tap MFMA GEMM ----------------
// grid (49, 4, 16) = (pixel tile, group, batch), block 256 (4 waves)
__global__ __launch_bounds__(256) void gconv_mfma(
    const bf16* __restrict__ xh, const bf16* __restrict__ wT,
    const float* __restrict__ scale, const float* __restrict__ bias,
    bf16* __restrict__ kh)
{
    int b = blockIdx.z, g = blockIdx.y;
    int p0 = blockIdx.x * 64;
    __shared__ bf16 As[64][72];
    __shared__ bf16 Bs[64][72];
    int t = threadIdx.x;
    int wv = t >> 6, lane = t & 63, q = lane >> 4, ln = lane & 15;
    f32x4 acc[4] = {};
    for (int tap = 0; tap < 9; tap++) {
        int dh = tap / 3 - 1, dw = tap % 3 - 1;
        __syncthreads();
        #pragma unroll
        for (int i = 0; i < 2; i++) {
            int slot = t + i * 256;
            int row = slot >> 3, cc = slot & 7;
            int p = p0 + row, h = p / HDIM, w = p % HDIM;
            int h2 = h + dh, w2 = w + dw;
            float4 v = {0.f, 0.f, 0.f, 0.f};
            if ((unsigned)h2 < HDIM && (unsigned)w2 < HDIM)
                v = *(const float4*)(xh + ((long)b * NPIX + h2 * HDIM + w2) * CDIM + g * 64 + cc * 8);
            *(float4*)&As[row][cc * 8] = v;
            *(float4*)&Bs[row][cc * 8] = *(const float4*)(wT + ((long)(g * 9 + tap) * 64 + row) * 64 + cc * 8);
        }
        __syncthreads();
        #pragma unroll
        for (int ks = 0; ks < 2; ks++) {
            s16x8 a = *(const s16x8*)&As[wv * 16 + ln][ks * 32 + q * 8];
            #pragma unroll
            for (int s = 0; s < 4; s++) {
                s16x8 bb = *(const s16x8*)&Bs[s * 16 + ln][ks * 32 + q * 8];
                acc[s] = __builtin_amdgcn_mfma_f32_16x16x32_bf16(a, bb, acc[s], 0, 0, 0);
            }
        }
    }
    __syncthreads();
    #pragma unroll
    for (int s = 0; s < 4; s++) {
        int co = g * 64 + s * 16 + ln;
        float sc = scale[co], bi = bias[co];
        #pragma unroll
        for (int r = 0; r < 4; r++) {
            float v = fmaxf(acc[s][r] * sc + bi, 0.f);
            As[wv * 16 + q * 4 + r][s * 16 + ln] = f2b(v);
        }
    }
    __syncthreads();
    #pragma unroll
    for (int i = 0; i < 2; i++) {
        int slot = t + i * 256;
        int row = slot >> 3, cc = slot & 7;
        *(float4*)(kh + ((long)b * NPIX + p0 + row) * CDIM + g * 64 + cc * 8) = *(const float4*)&As[row][cc * 8];
    }
}

// ---------------- 1x1 conv MFMA GEMM (NHWC): Y[n][m] = sum_k X[n][k] W[m][k] ----
// MODE 0: BN+ReLU   MODE 1: +bias only   MODE 2: BN only
// grid (49, M/64 ceil, 16), block 256
template<int MODE>
__global__ __launch_bounds__(256) void mfma_gemm(
    const bf16* __restrict__ Wt, const bf16* __restrict__ X0, const bf16* __restrict__ X1,
    int C0, int C1, int M,
    const float* __restrict__ scale, const float* __restrict__ bias,
    bf16* __restrict__ Y)
{
    int K = C0 + C1;
    int b = blockIdx.z;
    int p0 = blockIdx.x * 64;
    int m0 = blockIdx.y * 64;
    __shared__ bf16 As[64][72];
    __shared__ bf16 Bs[64][72];
    int t = threadIdx.x;
    int wv = t >> 6, lane = t & 63, q = lane >> 4, ln = lane & 15;
    f32x4 acc[4] = {};
    for (int k0 = 0; k0 < K; k0 += 64) {
        __syncthreads();
        #pragma unroll
        for (int i = 0; i < 2; i++) {
            int slot = t + i * 256;
            int row = slot >> 3, cc = slot & 7;
            int ch = k0 + cc * 8;
            const bf16* src;
            if (ch < C0) src = X0 + ((long)b * NPIX + p0 + row) * C0 + ch;
            else         src = X1 + ((long)b * NPIX + p0 + row) * C1 + (ch - C0);
            *(float4*)&As[row][cc * 8] = *(const float4*)src;

            int m = m0 + row;
            float4 v = {0.f, 0.f, 0.f, 0.f};
            if (m < M) v = *(const float4*)(Wt + (long)m * K + k0 + cc * 8);
            *(float4*)&Bs[row][cc * 8] = v;
        }
        __syncthreads();
        #pragma unroll
        for (int ks = 0; ks < 2; ks++) {
            s16x8 a = *(const s16x8*)&As[wv * 16 + ln][ks * 32 + q * 8];
            #pragma unroll
            for (int s = 0; s < 4; s++) {
                s16x8 bb = *(const s16x8*)&Bs[s * 16 + ln][ks * 32 + q * 8];
                acc[s] = __builtin_amdgcn_mfma_f32_16x16x32_bf16(a, bb, acc[s], 0, 0, 0);
            }
        }
    }
    __syncthreads();
    #pragma unroll
    for (int s = 0; s < 4; s++) {
        int m = m0 + s * 16 + ln;
        float sc = 1.f, bi;
        if (MODE == 0 || MODE == 2) { sc = scale[m]; bi = bias[m]; }
        else bi = bias[m];
        #pragma unroll
        for (int r = 0; r < 4; r++) {
            float v = acc[s][r] * sc + bi;
            if (MODE == 0) v = fmaxf(v, 0.f);
            As[wv * 16 + q * 4 + r][s * 16 + ln] = f2b(v);
        }
    }
    __syncthreads();
    #pragma unroll
    for (int i = 0; i < 2; i++) {
        int slot = t + i * 256;
        int row = slot >> 3, cc = slot & 7;
        if (m0 + cc * 8 + 8 <= M)
            *(float4*)(Y + ((long)b * NPIX + p0 + row) * M + m0 + cc * 8) = *(const float4*)&As[row][cc * 8];
    }
}

// ---------------- GroupNorm stats (NHWC wemb): block per (b, grp) ----------------
__global__ void gnstats(const bf16* __restrict__ wemb, float* __restrict__ mu_o, float* __restrict__ rs_o)
{
    int bg = blockIdx.x;              // b*32 + grp
    int b = bg >> 5, grp = bg & 31;
    const bf16* base = wemb + (long)b * NPIX * 288 + grp * 9;
    float s = 0.f, sq = 0.f;
    for (int p = threadIdx.x; p < NPIX; p += 256) {
        const bf16* e = base + (long)p * 288;
        #pragma unroll
        for (int j = 0; j < 9; j++) { float v = b2f(e[j]); s += v; sq += v * v; }
    }
    __shared__ float ss[256], sb[256];
    int t = threadIdx.x;
    ss[t] = s; sb[t] = sq;
    __syncthreads();
    for (int o = 128; o > 0; o >>= 1) {
        if (t < o) { ss[t] += ss[t + o]; sb[t] += sb[t + o]; }
        __syncthreads();
    }
    if (t == 0) {
        float m = ss[0] / 28224.f;
        float var = sb[0] / 28224.f - m * m;
        mu_o[bg] = m; rs_o[bg] = rsqrtf(fmaxf(var, 0.f) + 1e-5f);
    }
}

// ---------------- dynamic local conv + BN(b2) + swish (NHWC) ----------------
// thread = (b, pixel, group of 8 channels); grid 6272 * 256
__global__ __launch_bounds__(256) void dynconv(
    const bf16* __restrict__ xq, const bf16* __restrict__ wemb,
    const float* __restrict__ gmu, const float* __restrict__ grs,
    const float* __restrict__ gng, const float* __restrict__ gnb,
    const float* __restrict__ b2s, const float* __restrict__ b2b,
    bf16* __restrict__ y)
{
    int id = blockIdx.x * 256 + threadIdx.x;
    int grp = id & 31;
    int p = (id >> 5) % NPIX;
    int b = id / (NPIX * 32);
    int h = p / HDIM, w = p % HDIM;
    float mu = gmu[b * 32 + grp], rs = grs[b * 32 + grp];
    const bf16* wp = wemb + ((long)b * NPIX + p) * 288 + grp * 9;
    float wv[9];
    #pragma unroll
    for (int tp = 0; tp < 9; tp++)
        wv[tp] = (b2f(wp[tp]) - mu) * rs * gng[grp * 9 + tp] + gnb[grp * 9 + tp];
    float acc[8] = {};
    #pragma unroll
    for (int tp = 0; tp < 9; tp++) {
        int h2 = h + tp / 3 - 1, w2 = w + tp % 3 - 1;
        if ((unsigned)h2 >= HDIM || (unsigned)w2 >= HDIM) continue;
        const bf16* xp = xq + ((long)b * NPIX + h2 * HDIM + w2) * CDIM + grp * 8;
        s16x8 xv = *(const s16x8*)xp;
        const bf16* xb = (const bf16*)&xv;
        float wt = wv[tp];
        #pragma unroll
        for (int i = 0; i < 8; i++) acc[i] += b2f(xb[i]) * wt;
    }
    bf16 outv[8];
    #pragma unroll
    for (int i = 0; i < 8; i++) {
        int c = grp * 8 + i;
        float v = acc[i] * b2s[c] + b2b[c];
        outv[i] = f2b(v / (1.f + __expf(-v)));
    }
    *(float4*)(y + ((long)b * NPIX + p) * CDIM + grp * 8) = *(const float4*)outv;
}

// ---------------- GAP over (y + k), NHWC coalesced ----------------
// grid (16, 49), thread = channel
__global__ void gapk(const bf16* __restrict__ y, const bf16* __restrict__ k, float* __restrict__ gap)
{
    int b = blockIdx.x, chunk = blockIdx.y, c = threadIdx.x;
    float s = 0.f;
    for (int i = 0; i < 64; i++) {
        long off = ((long)b * NPIX + chunk * 64 + i) * CDIM + c;
        s += b2f(y[off]) + b2f(k[off]);
    }
    atomicAdd(&gap[b * 256 + c], s * (1.f / NPIX));
}

// ---------------- split attention ----------------
__global__ void attnk(const float* __restrict__ gap,
                      const float* __restrict__ s1w, const float* __restrict__ s1b,
                      const float* __restrict__ s1s, const float* __restrict__ s1bi,
                      const float* __restrict__ s2w, const float* __restrict__ s2b,
                      float* __restrict__ att)
{
    int b = blockIdx.x, t = threadIdx.x;   // 128 threads
    __shared__ float g[256], a1[128];
    for (int i = t; i < 256; i += 128) g[i] = gap[b * 256 + i];
    __syncthreads();
    float s = 0.f;
    for (int ci = 0; ci < 256; ci++) s += s1w[t * 256 + ci] * g[ci];
    s += s1b[t];
    s = s * s1s[t] + s1bi[t];
    a1[t] = fmaxf(s, 0.f);
    __syncthreads();
    for (int c = t; c < 256; c += 128) {
        float v0 = s2b[2 * c], v1 = s2b[2 * c + 1];
        for (int ci = 0; ci < 128; ci++) {
            float av = a1[ci];
            v0 += s2w[(2 * c) * 128 + ci] * av;
            v1 += s2w[(2 * c + 1) * 128 + ci] * av;
        }
        float m = fmaxf(v0, v1);
        float e0 = __expf(v0 - m), e1 = __expf(v1 - m);
        float inv = 1.f / (e0 + e1);
        att[(b * 256 + c) * 2 + 0] = e0 * inv;
        att[(b * 256 + c) * 2 + 1] = e1 * inv;
    }
}

// ---------------- final: combine + NHWC->NCHW fp32 out ----------------
// grid (49, 4, 16) = (p tile, c tile, b)
__global__ __launch_bounds__(256) void finalk(
    const bf16* __restrict__ y, const bf16* __restrict__ k,
    const float* __restrict__ att, float* __restrict__ out)
{
    int b = blockIdx.z, c0 = blockIdx.y * 64, p0 = blockIdx.x * 64;
    __shared__ bf16 Ys[64][72], Ks[64][72];
    int t = threadIdx.x;
    #pragma unroll
    for (int i = 0; i < 2; i++) {
        int slot = t + i * 256;
        int row = slot >> 3, cc = slot & 7;
        long off = ((long)b * NPIX + p0 + row) * CDIM + c0 + cc * 8;
        *(float4*)&Ys[row][cc * 8] = *(const float4*)(y + off);
        *(float4*)&Ks[row][cc * 8] = *(const float4*)(k + off);
    }
    __syncthreads();
    int c_l = t >> 2, pc = t & 3;
    int c = c0 + c_l;
    float a0 = att[(b * 256 + c) * 2], a1 = att[(b * 256 + c) * 2 + 1];
    float4 o[4];
    float* of = (float*)o;
    #pragma unroll
    for (int j = 0; j < 16; j++) {
        int p = pc * 16 + j;
        of[j] = b2f(Ys[p][c_l]) * a0 + b2f(Ks[p][c_l]) * a1;
    }
    float* dst = out + ((long)b * CDIM + c) * NPIX + p0 + pc * 16;
    #pragma unroll
    for (int j = 0; j < 4; j++) ((float4*)dst)[j] = o[j];
}

extern "C" void kernel_launch(void* const* d_in, const int* in_sizes, int n_in,
                              void* d_out, int out_size, void* d_ws, size_t ws_size,
                              hipStream_t stream)
{
    const float* x    = (const float*)d_in[0];
    const float* ke_w = (const float*)d_in[1];
    const float* ke_g = (const float*)d_in[2];
    const float* ke_b = (const float*)d_in[3];
    const float* ke_m = (const float*)d_in[4];
    const float* ke_v = (const float*)d_in[5];
    const float* e1_w = (const float*)d_in[6];
    const float* e1_g = (const float*)d_in[7];
    const float* e1_b = (const float*)d_in[8];
    const float* e1_m = (const float*)d_in[9];
    const float* e1_v = (const float*)d_in[10];
    const float* e2_w = (const float*)d_in[11];
    const float* e2_b = (const float*)d_in[12];
    const float* gng  = (const float*)d_in[13];
    const float* gnb  = (const float*)d_in[14];
    const float* c1_w = (const float*)d_in[15];
    const float* c1_g = (const float*)d_in[16];
    const float* c1_b = (const float*)d_in[17];
    const float* c1_m = (const float*)d_in[18];
    const float* c1_v = (const float*)d_in[19];
    const float* b2_g = (const float*)d_in[20];
    const float* b2_b = (const float*)d_in[21];
    const float* b2_m = (const float*)d_in[22];
    const float* b2_v = (const float*)d_in[23];
    const float* s1_w = (const float*)d_in[24];
    const float* s1_b = (const float*)d_in[25];
    const float* s1_g = (const float*)d_in[26];
    const float* s1_bb= (const float*)d_in[27];
    const float* s1_m = (const float*)d_in[28];
    const float* s1_v = (const float*)d_in[29];
    const float* s2_w = (const float*)d_in[30];
    const float* s2_b = (const float*)d_in[31];

    float* fold = (float*)d_ws;
    bf16* wsb   = (bf16*)((char*)d_ws + 65536);
    // NHWC activation regions (bf16 elems):
    bf16* xh   = wsb;                     // 12,845,056  (aliased by yb after c1)
    bf16* kh   = xh + 12845056L;          // 12,845,056
    bf16* wemb = kh + 12845056L;          // 14,450,688
    bf16* w1   = wemb + 14450688L;        // region 12,845,056 (w1 6.4M, then xq)
    bf16* xq   = w1;                      // alias (w1 dead before c1)
    bf16* yb   = xh;                      // alias (xh dead before dynconv)
    bf16* kewT = w1 + 12845056L;          // 147,456
    bf16* e1wb = kewT + 147456L;          // 65,536
    bf16* e2wb = e1wb + 65536L;           // 36,864
    bf16* c1wb = e2wb + 36864L;           // 65,536

    fold_params<<<dim3(1), dim3(512), 0, stream>>>(
        ke_g, ke_b, ke_m, ke_v, e1_g, e1_b, e1_m, e1_v, e2_b,
        c1_g, c1_b, c1_m, c1_v, b2_g, b2_b, b2_m, b2_v,
        s1_g, s1_bb, s1_m, s1_v, fold);

    zero_gap<<<dim3(16), dim3(256), 0, stream>>>(fold + O_GAP);

    cvt_w<<<dim3(256), dim3(256), 0, stream>>>(e1_w, e1wb, 65536);
    cvt_w<<<dim3(144), dim3(256), 0, stream>>>(e2_w, e2wb, 36864);
    cvt_w<<<dim3(256), dim3(256), 0, stream>>>(c1_w, c1wb, 65536);
    make_kewT<<<dim3(576), dim3(256), 0, stream>>>(ke_w, kewT);

    cvt_x<<<dim3(49, 16), dim3(256), 0, stream>>>(x, xh);

    gconv_mfma<<<dim3(49, 4, 16), dim3(256), 0, stream>>>(
        xh, kewT, fold + O_KE_S, fold + O_KE_B, kh);

    mfma_gemm<0><<<dim3(49, 2, 16), dim3(256), 0, stream>>>(
        e1wb, xh, kh, 256, 256, 128, fold + O_E1_S, fold + O_E1_B, w1);

    mfma_gemm<1><<<dim3(49, 5, 16), dim3(256), 0, stream>>>(
        e2wb, w1, (const bf16*)nullptr, 128, 0, 288, (const float*)nullptr, fold + O_E2B, wemb);

    gnstats<<<dim3(512), dim3(256), 0, stream>>>(wemb, fold + O_GN_MU, fold + O_GN_RS);

    mfma_gemm<2><<<dim3(49, 4, 16), dim3(256), 0, stream>>>(
        c1wb, xh, (const bf16*)nullptr, 256, 0, 256, fold + O_C1_S, fold + O_C1_B, xq);

    dynconv<<<dim3(6272), dim3(256), 0, stream>>>(
        xq, wemb, fold + O_GN_MU, fold + O_GN_RS, gng, gnb,
        fold + O_B2_S, fold + O_B2_B, yb);

    gapk<<<dim3(16, 49), dim3(256), 0, stream>>>(yb, kh, fold + O_GAP);

    attnk<<<dim3(16), dim3(128), 0, stream>>>(
        fold + O_GAP, s1_w, s1_b, fold + O_S1_S, fold + O_S1_B, s2_w, s2_b, fold + O_ATT);

    finalk<<<dim3(49, 4, 16), dim3(256), 0, stream>>>(yb, kh, fold + O_ATT, (float*)d_out);
}